// Round 6
// baseline (443.184 us; speedup 1.0000x reference)
//
#include <hip/hip_runtime.h>
#include <cstdint>
#include <cstddef>

typedef __attribute__((ext_vector_type(8))) short short8;     // 8 bf16 (4 VGPRs)
typedef __attribute__((ext_vector_type(4))) float f32x4;      // MFMA acc
typedef __attribute__((ext_vector_type(4))) unsigned short u16x4;

#define ASYNC16(gp, lp) \
  __builtin_amdgcn_global_load_lds((const __attribute__((address_space(1))) unsigned int*)(gp), \
                                   (__attribute__((address_space(3))) unsigned int*)(lp), 16, 0, 0)

__device__ __forceinline__ unsigned short f2b(float f) {
  union { float f; unsigned int u; } c; c.f = f;
  unsigned int u = c.u;
  return (unsigned short)((u + 0x7fffu + ((u >> 16) & 1u)) >> 16);
}

// ---------------- conversion kernels ----------------

__global__ void cvt_bf16(const float* __restrict__ X, unsigned short* __restrict__ Y, int n) {
  int i = (blockIdx.x * 256 + threadIdx.x) * 4;
  if (i < n) {
    const float* px = X + i;
    float a = px[0], b = px[1], c = px[2], d = px[3];
    u16x4 u;
    u[0] = f2b(a); u[1] = f2b(b); u[2] = f2b(c); u[3] = f2b(d);
    *(u16x4*)(Y + i) = u;
  }
}

// W [Kd][Nd] fp32 -> WT [Nd][Kd] bf16, 64x64 tiles
__global__ void transpose_cvt(const float* __restrict__ W, unsigned short* __restrict__ WT,
                              int Kd, int Nd) {
  __shared__ unsigned short Ts[64][65];
  int n0 = blockIdx.x * 64, k0 = blockIdx.y * 64;
  int tid = threadIdx.x;
  for (int idx = tid; idx < 4096; idx += 256) {
    int lr = idx >> 6, lc = idx & 63;
    Ts[lr][lc] = f2b(W[(size_t)(k0 + lr) * Nd + n0 + lc]);
  }
  __syncthreads();
  for (int idx = tid; idx < 4096; idx += 256) {
    int nr = idx >> 6, kc = idx & 63;
    WT[(size_t)(n0 + nr) * Kd + k0 + kc] = Ts[kc][nr];
  }
}

// ---------------- GEMM 1: qkv = x @ w_attn + b, scatter to q/k/vT ----------------
// 128x192 tile (wave-tile 64x96), grid 64x12 = 768 blocks = exactly 3/CU: zero
// dispatch tail. r3/r4/r5 proved staging micro-structure neutral -> plain
// m97-style 2-barrier loop with global_load_lds.

__global__ __launch_bounds__(256, 3) void gemm_qkv(
    const unsigned short* __restrict__ A,   // xb [8192][768]
    const unsigned short* __restrict__ Bt,  // waT [2304][768]
    const float* __restrict__ bias,         // [2304]
    unsigned short* __restrict__ q,         // [96][1024][64], pre-scaled by 0.125*log2(e)
    unsigned short* __restrict__ k,         // [96][1024][64]
    unsigned short* __restrict__ vT)        // [96][64][1024]
{
  __shared__ unsigned short As[128 * 32];   // 8 KB
  __shared__ unsigned short Bs[192 * 32];   // 12 KB
  const int tid = threadIdx.x;
  const int w = tid >> 6, lane = tid & 63;
  const int wm = w >> 1, wn = w & 1;        // 2x2 waves; wave-tile 64 x 96
  const int lr = lane & 15, lq = lane >> 4;
  const int m0 = blockIdx.x * 128, n0 = blockIdx.y * 192;
  const f32x4 fzero = {0.f, 0.f, 0.f, 0.f};

  f32x4 acc[4][6];
  for (int i = 0; i < 4; ++i) for (int j = 0; j < 6; ++j) acc[i][j] = fzero;

  // staging geometry: chunk = 1024 B per wave; A has 2 chunks, B has 3
  int sbase[3], srow[3], skc[3];
  for (int c = 0; c < 3; ++c) {
    sbase[c] = (c * 4 + w) * 1024;
    int e = (sbase[c] >> 1) + lane * 8;
    srow[c] = e >> 5; skc[c] = e & 31;
  }

  for (int kk0 = 0; kk0 < 768; kk0 += 32) {
    __syncthreads();
    for (int c = 0; c < 2; ++c)
      ASYNC16(A + (size_t)(m0 + srow[c]) * 768 + kk0 + skc[c], (char*)As + sbase[c]);
    for (int c = 0; c < 3; ++c)
      ASYNC16(Bt + (size_t)(n0 + srow[c]) * 768 + kk0 + skc[c], (char*)Bs + sbase[c]);
    __builtin_amdgcn_s_waitcnt(0);
    __syncthreads();

    short8 a[4], b[6];
    for (int i = 0; i < 4; ++i)
      a[i] = *(const short8*)(As + (wm * 64 + i * 16 + lr) * 32 + lq * 8);
    for (int j = 0; j < 6; ++j)
      b[j] = *(const short8*)(Bs + (wn * 96 + j * 16 + lr) * 32 + lq * 8);
    for (int i = 0; i < 4; ++i)
      for (int j = 0; j < 6; ++j)
        acc[i][j] = __builtin_amdgcn_mfma_f32_16x16x32_bf16(a[i], b[j], acc[i][j], 0, 0, 0);
  }

  // epilogue: n0 is a multiple of 192; 768/192=4 -> section block-uniform
  const int sec = n0 / 768;                     // 0=q, 1=k, 2=v
  const float QSCALE = 0.18033688011112042f;    // 0.125 * log2(e)
  for (int j = 0; j < 6; ++j) {
    int col = n0 + wn * 96 + j * 16 + lr;
    int cc = col - sec * 768;
    int h = cc >> 6, d = cc & 63;
    float bv = bias[col];
    for (int i = 0; i < 4; ++i) {
      int row0 = m0 + wm * 64 + i * 16 + lq * 4;
      int bidx = row0 >> 10, t0 = row0 & 1023;
      int bh = bidx * 12 + h;
      if (sec == 0) {
        for (int r = 0; r < 4; ++r)
          q[((size_t)bh * 1024 + t0 + r) * 64 + d] = f2b((acc[i][j][r] + bv) * QSCALE);
      } else if (sec == 1) {
        for (int r = 0; r < 4; ++r)
          k[((size_t)bh * 1024 + t0 + r) * 64 + d] = f2b(acc[i][j][r] + bv);
      } else {
        u16x4 pv;
        pv[0] = f2b(acc[i][j][0] + bv);
        pv[1] = f2b(acc[i][j][1] + bv);
        pv[2] = f2b(acc[i][j][2] + bv);
        pv[3] = f2b(acc[i][j][3] + bv);
        *(u16x4*)(vT + ((size_t)bh * 64 + d) * 1024 + t0) = pv;
      }
    }
  }
}

// ---------------- flash attention (no online-softmax: scores bounded, exp2 safe) ----
// grid 768: block g = (qp = g/96, bh = g%96); processes q-tiles qp and 15-qp
// (64 rows each) -> every block does exactly 17 k-tile units.
// 4 waves x 16 q-rows each; K/V software-pipelined through registers.

__global__ __launch_bounds__(256, 2) void attn(
    const unsigned short* __restrict__ q,
    const unsigned short* __restrict__ kk,
    const unsigned short* __restrict__ vT,
    unsigned short* __restrict__ y)         // [8192][768]
{
  __shared__ unsigned short Qs[64 * 72];    // stride 72: 2-way bank alias (free)
  __shared__ unsigned short Ks[64 * 72];
  __shared__ unsigned short Vt[64 * 72];    // [d][t]
  __shared__ unsigned short Ps[4 * 16 * 72];

  const int tid = threadIdx.x;
  const int w = tid >> 6, lane = tid & 63;
  const int lr = lane & 15, lq = lane >> 4;
  const int g = blockIdx.x;
  const int bh = g % 96;
  const int qp = g / 96;
  const int b = bh / 12, h = bh - b * 12;
  const f32x4 fzero = {0.f, 0.f, 0.f, 0.f};

  unsigned short* Pw = Ps + w * 16 * 72;
  const unsigned short* kbase = kk + (size_t)bh * 65536;
  const unsigned short* vbase = vT + (size_t)bh * 65536;

  const int c0 = tid, c1 = tid + 256;       // staging element-chunk ids (row=c>>3)
  short8 kreg[2], vreg[2];

  for (int half = 0; half < 2; ++half) {
    const int qt = half ? (15 - qp) : qp;
    const int q0 = qt * 64;

    __syncthreads();                        // prior half's LDS reads complete
    {
      const unsigned short* qptr = q + ((size_t)bh * 1024 + q0) * 64;
      short8 q0r = *(const short8*)(qptr + (size_t)c0 * 8);
      short8 q1r = *(const short8*)(qptr + (size_t)c1 * 8);
      *(short8*)(Qs + (c0 >> 3) * 72 + (c0 & 7) * 8) = q0r;
      *(short8*)(Qs + (c1 >> 3) * 72 + (c1 & 7) * 8) = q1r;
    }
    // prefetch kt = 0
    kreg[0] = *(const short8*)(kbase + (size_t)c0 * 8);
    kreg[1] = *(const short8*)(kbase + (size_t)c1 * 8);
    vreg[0] = *(const short8*)(vbase + (size_t)(c0 >> 3) * 1024 + (c0 & 7) * 8);
    vreg[1] = *(const short8*)(vbase + (size_t)(c1 >> 3) * 1024 + (c1 & 7) * 8);

    f32x4 o[4];
    float l_s[4];
    for (int jd = 0; jd < 4; ++jd) o[jd] = fzero;
    for (int r = 0; r < 4; ++r) l_s[r] = 0.0f;

    for (int kt = 0; kt <= qt; ++kt) {
      __syncthreads();                      // prev iter's LDS reads done (+Q writes visible)
      *(short8*)(Ks + (c0 >> 3) * 72 + (c0 & 7) * 8) = kreg[0];
      *(short8*)(Ks + (c1 >> 3) * 72 + (c1 & 7) * 8) = kreg[1];
      *(short8*)(Vt + (c0 >> 3) * 72 + (c0 & 7) * 8) = vreg[0];
      *(short8*)(Vt + (c1 >> 3) * 72 + (c1 & 7) * 8) = vreg[1];
      __syncthreads();
      if (kt < qt) {                        // prefetch next tile; overlaps compute below
        const unsigned short* kp = kbase + (size_t)(kt + 1) * 4096;
        const unsigned short* vp = vbase + (size_t)(kt + 1) * 64;
        kreg[0] = *(const short8*)(kp + (size_t)c0 * 8);
        kreg[1] = *(const short8*)(kp + (size_t)c1 * 8);
        vreg[0] = *(const short8*)(vp + (size_t)(c0 >> 3) * 1024 + (c0 & 7) * 8);
        vreg[1] = *(const short8*)(vp + (size_t)(c1 >> 3) * 1024 + (c1 & 7) * 8);
      }

      // S = Q K^T (q pre-scaled by 0.125*log2e)
      f32x4 s[4];
      for (int j = 0; j < 4; ++j) s[j] = fzero;
      for (int ks = 0; ks < 2; ++ks) {
        short8 aq = *(const short8*)(Qs + (w * 16 + lr) * 72 + ks * 32 + lq * 8);
        short8 bk[4];
        for (int j = 0; j < 4; ++j)
          bk[j] = *(const short8*)(Ks + (j * 16 + lr) * 72 + ks * 32 + lq * 8);
        for (int j = 0; j < 4; ++j)
          s[j] = __builtin_amdgcn_mfma_f32_16x16x32_bf16(aq, bk[j], s[j], 0, 0, 0);
      }
      if (kt == qt) {                       // diagonal tile: causal mask
        int rowt = w * 16 + lq * 4;
        for (int j = 0; j < 4; ++j) {
          int colt = j * 16 + lr;
          for (int r = 0; r < 4; ++r)
            if (colt > rowt + r) s[j][r] = -1e30f;
        }
      }
      // p = exp2(s); accumulate l per-lane; stash P (C-layout -> A-layout via LDS)
      for (int r = 0; r < 4; ++r) {
        int prow = (lq * 4 + r) * 72;
        float acc = 0.0f;
        for (int j = 0; j < 4; ++j) {
          float p = __builtin_amdgcn_exp2f(s[j][r]);
          acc += p;
          union { float f; unsigned int u; } cv; cv.f = p;
          Pw[prow + j * 16 + lr] = (unsigned short)((cv.u + 0x8000u) >> 16);
        }
        l_s[r] += acc;
      }
      // O += P V (same-wave DS in-order; compiler emits lgkm waits)
      for (int ks = 0; ks < 2; ++ks) {
        short8 ap = *(const short8*)(Pw + lr * 72 + ks * 32 + lq * 8);
        short8 bv[4];
        for (int jd = 0; jd < 4; ++jd)
          bv[jd] = *(const short8*)(Vt + (jd * 16 + lr) * 72 + ks * 32 + lq * 8);
        for (int jd = 0; jd < 4; ++jd)
          o[jd] = __builtin_amdgcn_mfma_f32_16x16x32_bf16(ap, bv[jd], o[jd], 0, 0, 0);
      }
    }

    // epilogue: reduce l across the 16 col-lanes, scale, store
    for (int r = 0; r < 4; ++r) {
      float lv = l_s[r];
      for (int off = 1; off < 16; off <<= 1)
        lv += __shfl_xor(lv, off, 16);
      l_s[r] = 1.0f / lv;
    }
    int t = q0 + w * 16 + lq * 4;
    for (int jd = 0; jd < 4; ++jd) {
      int d = jd * 16 + lr;
      for (int r = 0; r < 4; ++r)
        y[((size_t)b * 1024 + t + r) * 768 + h * 64 + d] = f2b(o[jd][r] * l_s[r]);
    }
  }
}

// ---------------- GEMM 2: out = y @ w_proj + b ----------------
// 64x128 tile, grid 128x6 = 768 blocks = exactly 3/CU: zero dispatch tail
// (old 128x128 grid was 384 = 1.5/CU, the worst-shaped dispatch).

__global__ __launch_bounds__(256, 3) void gemm_proj(
    const unsigned short* __restrict__ A,   // y [8192][768]
    const unsigned short* __restrict__ Bt,  // wpT [768][768]
    const float* __restrict__ bias,         // [768]
    float* __restrict__ out)                // [8192][768] fp32
{
  __shared__ unsigned short As[64 * 32];    // 4 KB
  __shared__ unsigned short Bs[128 * 32];   // 8 KB
  const int tid = threadIdx.x;
  const int w = tid >> 6, lane = tid & 63;
  const int wm = w >> 1, wn = w & 1;        // wave-tile 32 x 64
  const int lr = lane & 15, lq = lane >> 4;
  const int m0 = blockIdx.x * 64, n0 = blockIdx.y * 128;
  const f32x4 fzero = {0.f, 0.f, 0.f, 0.f};

  f32x4 acc[2][4];
  for (int i = 0; i < 2; ++i) for (int j = 0; j < 4; ++j) acc[i][j] = fzero;

  int sbase[2], srow[2], skc[2];
  for (int c = 0; c < 2; ++c) {
    sbase[c] = (c * 4 + w) * 1024;
    int e = (sbase[c] >> 1) + lane * 8;
    srow[c] = e >> 5; skc[c] = e & 31;
  }

  for (int kk0 = 0; kk0 < 768; kk0 += 32) {
    __syncthreads();
    if (w < 1 || true) {                    // A: 4 chunks of 1KB (one per wave)
      int e = (w * 1024 >> 1) + lane * 8;
      ASYNC16(A + (size_t)(m0 + (e >> 5)) * 768 + kk0 + (e & 31), (char*)As + w * 1024);
    }
    for (int c = 0; c < 2; ++c)
      ASYNC16(Bt + (size_t)(n0 + srow[c]) * 768 + kk0 + skc[c], (char*)Bs + sbase[c]);
    __builtin_amdgcn_s_waitcnt(0);
    __syncthreads();

    short8 a[2], b[4];
    for (int i = 0; i < 2; ++i)
      a[i] = *(const short8*)(As + (wm * 32 + i * 16 + lr) * 32 + lq * 8);
    for (int j = 0; j < 4; ++j)
      b[j] = *(const short8*)(Bs + (wn * 64 + j * 16 + lr) * 32 + lq * 8);
    for (int i = 0; i < 2; ++i)
      for (int j = 0; j < 4; ++j)
        acc[i][j] = __builtin_amdgcn_mfma_f32_16x16x32_bf16(a[i], b[j], acc[i][j], 0, 0, 0);
  }

  for (int j = 0; j < 4; ++j) {
    int col = n0 + wn * 64 + j * 16 + lr;
    float bv = bias[col];
    for (int i = 0; i < 2; ++i) {
      int row0 = m0 + wm * 32 + i * 16 + lq * 4;
      for (int r = 0; r < 4; ++r)
        out[(size_t)(row0 + r) * 768 + col] = acc[i][j][r] + bv;
    }
  }
}

// ---------------- launch ----------------

extern "C" void kernel_launch(void* const* d_in, const int* in_sizes, int n_in,
                              void* d_out, int out_size, void* d_ws, size_t ws_size,
                              hipStream_t stream) {
  const float* x      = (const float*)d_in[0];
  const float* w_attn = (const float*)d_in[1];
  const float* b_attn = (const float*)d_in[2];
  const float* w_proj = (const float*)d_in[3];
  const float* b_proj = (const float*)d_in[4];
  float* out = (float*)d_out;

  char* p = (char*)d_ws;
  unsigned short* xb  = (unsigned short*)p; p += (size_t)8192 * 768 * 2;
  unsigned short* waT = (unsigned short*)p; p += (size_t)2304 * 768 * 2;
  unsigned short* wpT = (unsigned short*)p; p += (size_t)768 * 768 * 2;
  unsigned short* qb  = (unsigned short*)p; p += (size_t)96 * 1024 * 64 * 2;
  unsigned short* kb  = (unsigned short*)p; p += (size_t)96 * 1024 * 64 * 2;
  unsigned short* vTb = (unsigned short*)p; p += (size_t)96 * 64 * 1024 * 2;
  unsigned short* yb  = (unsigned short*)p; p += (size_t)8192 * 768 * 2;

  cvt_bf16<<<6144, 256, 0, stream>>>(x, xb, 8192 * 768);
  transpose_cvt<<<dim3(36, 12), 256, 0, stream>>>(w_attn, waT, 768, 2304);
  transpose_cvt<<<dim3(12, 12), 256, 0, stream>>>(w_proj, wpT, 768, 768);
  gemm_qkv<<<dim3(64, 12), 256, 0, stream>>>(xb, waT, b_attn, qb, kb, vTb);
  attn<<<768, 256, 0, stream>>>(qb, kb, vTb, yb);
  gemm_proj<<<dim3(128, 6), 256, 0, stream>>>(yb, wpT, b_proj, out);
}

// Round 7
// 188.988 us; speedup vs baseline: 2.3450x; 2.3450x over previous
//
#include <hip/hip_runtime.h>
#include <cstdint>
#include <cstddef>

typedef __attribute__((ext_vector_type(8))) short short8;     // 8 bf16 (4 VGPRs)
typedef __attribute__((ext_vector_type(4))) float f32x4;      // MFMA acc
typedef __attribute__((ext_vector_type(4))) unsigned short u16x4;
typedef __attribute__((ext_vector_type(4))) float float4v;

#define ASYNC16(gp, lp) \
  __builtin_amdgcn_global_load_lds((const __attribute__((address_space(1))) unsigned int*)(gp), \
                                   (__attribute__((address_space(3))) unsigned int*)(lp), 16, 0, 0)

__device__ __forceinline__ unsigned short f2b(float f) {
  union { float f; unsigned int u; } c; c.f = f;
  unsigned int u = c.u;
  return (unsigned short)((u + 0x7fffu + ((u >> 16) & 1u)) >> 16);
}

// ---------------- merged prep: x->bf16, w_attn->waT, w_proj->wpT ----------------
// blocks [0,3072): cvt 8 elem/thread; [3072,3504): w_attn 64x64 transpose tiles;
// [3504,3648): w_proj tiles. Disjoint outputs, one launch instead of three.

__global__ __launch_bounds__(256) void prep(
    const float* __restrict__ x, unsigned short* __restrict__ xb,
    const float* __restrict__ w_attn, unsigned short* __restrict__ waT,
    const float* __restrict__ w_proj, unsigned short* __restrict__ wpT) {
  __shared__ unsigned short Ts[64][65];
  const int bb = blockIdx.x;
  const int tid = threadIdx.x;
  if (bb < 3072) {
    int i = (bb * 256 + tid) * 8;
    const float* px = x + i;
    short8 v;
    for (int e = 0; e < 8; ++e) ((unsigned short*)&v)[e] = f2b(px[e]);
    *(short8*)(xb + i) = v;
    return;
  }
  const float* W; unsigned short* WT; int Kd, Nd, n0, k0;
  if (bb < 3504) {
    int t = bb - 3072; W = w_attn; WT = waT; Kd = 768; Nd = 2304;
    n0 = (t % 36) * 64; k0 = (t / 36) * 64;
  } else {
    int t = bb - 3504; W = w_proj; WT = wpT; Kd = 768; Nd = 768;
    n0 = (t % 12) * 64; k0 = (t / 12) * 64;
  }
  for (int idx = tid; idx < 4096; idx += 256) {
    int lr = idx >> 6, lc = idx & 63;
    Ts[lr][lc] = f2b(W[(size_t)(k0 + lr) * Nd + n0 + lc]);
  }
  __syncthreads();
  for (int idx = tid; idx < 4096; idx += 256) {
    int nr = idx >> 6, kc = idx & 63;
    WT[(size_t)(n0 + nr) * Kd + k0 + kc] = Ts[kc][nr];
  }
}

// ---------------- GEMM 1: qkv = x @ w_attn + b, scatter to q/k/vT ----------------
// r3 version (measured 62.5 us): 128x128 tile, grid 64x18, plain 2-barrier
// K-loop with global_load_lds width-16. r4 (dbuf+vmcnt), r5 (buffer_load+ds_write),
// r6 (128x192 tile) were all neutral-or-worse: ~28 B/cyc/CU L2->LDS appears to
// be the ceiling for this shape. 192-wide epilogue = 30x write amplification (r6).

__global__ __launch_bounds__(256, 2) void gemm_qkv(
    const unsigned short* __restrict__ A,   // xb [8192][768]
    const unsigned short* __restrict__ Bt,  // waT [2304][768]
    const float* __restrict__ bias,         // [2304]
    unsigned short* __restrict__ q,         // [96][1024][64], pre-scaled by 0.125*log2(e)
    unsigned short* __restrict__ k,         // [96][1024][64]
    unsigned short* __restrict__ vT)        // [96][64][1024]
{
  __shared__ unsigned short As[128 * 32];
  __shared__ unsigned short Bs[128 * 32];
  const int tid = threadIdx.x;
  const int w = tid >> 6, lane = tid & 63;
  const int wm = w >> 1, wn = w & 1;
  const int lr = lane & 15, lq = lane >> 4;
  const int m0 = blockIdx.x * 128, n0 = blockIdx.y * 128;
  const f32x4 fzero = {0.f, 0.f, 0.f, 0.f};

  f32x4 acc[4][4];
  for (int i = 0; i < 4; ++i) for (int j = 0; j < 4; ++j) acc[i][j] = fzero;

  for (int kk0 = 0; kk0 < 768; kk0 += 32) {
    __syncthreads();
    for (int c = 0; c < 2; ++c) {
      int base = (c * 4 + w) * 1024;            // byte offset into 8 KB LDS tile
      int e = (base >> 1) + lane * 8;           // element index
      int row = e >> 5, kc = e & 31;
      ASYNC16(A  + (size_t)(m0 + row) * 768 + kk0 + kc, (char*)As + base);
      ASYNC16(Bt + (size_t)(n0 + row) * 768 + kk0 + kc, (char*)Bs + base);
    }
    __builtin_amdgcn_s_waitcnt(0);
    __syncthreads();

    short8 a[4], b[4];
    for (int i = 0; i < 4; ++i)
      a[i] = *(const short8*)(As + (wm * 64 + i * 16 + lr) * 32 + lq * 8);
    for (int j = 0; j < 4; ++j)
      b[j] = *(const short8*)(Bs + (wn * 64 + j * 16 + lr) * 32 + lq * 8);
    for (int i = 0; i < 4; ++i)
      for (int j = 0; j < 4; ++j)
        acc[i][j] = __builtin_amdgcn_mfma_f32_16x16x32_bf16(a[i], b[j], acc[i][j], 0, 0, 0);
  }

  // epilogue: each 128-col tile lies entirely in one of q/k/v
  const int colbase = n0 + wn * 64;
  const int sec = colbase / 768;                // 0=q, 1=k, 2=v (block-uniform)
  const float QSCALE = 0.18033688011112042f;    // 0.125 * log2(e)
  for (int j = 0; j < 4; ++j) {
    int col = colbase + j * 16 + lr;
    int cc = col - sec * 768;
    int h = cc >> 6, d = cc & 63;
    float bv = bias[col];
    for (int i = 0; i < 4; ++i) {
      int row0 = m0 + wm * 64 + i * 16 + lq * 4;
      int bidx = row0 >> 10, t0 = row0 & 1023;
      int bh = bidx * 12 + h;
      if (sec == 0) {
        for (int r = 0; r < 4; ++r)
          q[((size_t)bh * 1024 + t0 + r) * 64 + d] = f2b((acc[i][j][r] + bv) * QSCALE);
      } else if (sec == 1) {
        for (int r = 0; r < 4; ++r)
          k[((size_t)bh * 1024 + t0 + r) * 64 + d] = f2b(acc[i][j][r] + bv);
      } else {
        u16x4 pv;
        pv[0] = f2b(acc[i][j][0] + bv);
        pv[1] = f2b(acc[i][j][1] + bv);
        pv[2] = f2b(acc[i][j][2] + bv);
        pv[3] = f2b(acc[i][j][3] + bv);
        *(u16x4*)(vT + ((size_t)bh * 64 + d) * 1024 + t0) = pv;
      }
    }
  }
}

// ---------------- flash attention (no online-softmax: scores bounded, exp2 safe) ----
// grid 768: block g = (qp = g/96, bh = g%96); processes q-tiles qp and 15-qp
// (64 rows each) -> every block does exactly 17 k-tile units.
// 4 waves x 16 q-rows each; K/V software-pipelined through registers.

__global__ __launch_bounds__(256, 2) void attn(
    const unsigned short* __restrict__ q,
    const unsigned short* __restrict__ kk,
    const unsigned short* __restrict__ vT,
    unsigned short* __restrict__ y)         // [8192][768]
{
  __shared__ unsigned short Qs[64 * 72];    // stride 72: 2-way bank alias (free)
  __shared__ unsigned short Ks[64 * 72];
  __shared__ unsigned short Vt[64 * 72];    // [d][t]
  __shared__ unsigned short Ps[4 * 16 * 72];

  const int tid = threadIdx.x;
  const int w = tid >> 6, lane = tid & 63;
  const int lr = lane & 15, lq = lane >> 4;
  const int g = blockIdx.x;
  const int bh = g % 96;
  const int qp = g / 96;
  const int b = bh / 12, h = bh - b * 12;
  const f32x4 fzero = {0.f, 0.f, 0.f, 0.f};

  unsigned short* Pw = Ps + w * 16 * 72;
  const unsigned short* kbase = kk + (size_t)bh * 65536;
  const unsigned short* vbase = vT + (size_t)bh * 65536;

  const int c0 = tid, c1 = tid + 256;       // staging element-chunk ids (row=c>>3)
  short8 kreg[2], vreg[2];

  for (int half = 0; half < 2; ++half) {
    const int qt = half ? (15 - qp) : qp;
    const int q0 = qt * 64;

    __syncthreads();                        // prior half's LDS reads complete
    {
      const unsigned short* qptr = q + ((size_t)bh * 1024 + q0) * 64;
      short8 q0r = *(const short8*)(qptr + (size_t)c0 * 8);
      short8 q1r = *(const short8*)(qptr + (size_t)c1 * 8);
      *(short8*)(Qs + (c0 >> 3) * 72 + (c0 & 7) * 8) = q0r;
      *(short8*)(Qs + (c1 >> 3) * 72 + (c1 & 7) * 8) = q1r;
    }
    // prefetch kt = 0
    kreg[0] = *(const short8*)(kbase + (size_t)c0 * 8);
    kreg[1] = *(const short8*)(kbase + (size_t)c1 * 8);
    vreg[0] = *(const short8*)(vbase + (size_t)(c0 >> 3) * 1024 + (c0 & 7) * 8);
    vreg[1] = *(const short8*)(vbase + (size_t)(c1 >> 3) * 1024 + (c1 & 7) * 8);

    f32x4 o[4];
    float l_s[4];
    for (int jd = 0; jd < 4; ++jd) o[jd] = fzero;
    for (int r = 0; r < 4; ++r) l_s[r] = 0.0f;

    for (int kt = 0; kt <= qt; ++kt) {
      __syncthreads();                      // prev iter's LDS reads done (+Q writes visible)
      *(short8*)(Ks + (c0 >> 3) * 72 + (c0 & 7) * 8) = kreg[0];
      *(short8*)(Ks + (c1 >> 3) * 72 + (c1 & 7) * 8) = kreg[1];
      *(short8*)(Vt + (c0 >> 3) * 72 + (c0 & 7) * 8) = vreg[0];
      *(short8*)(Vt + (c1 >> 3) * 72 + (c1 & 7) * 8) = vreg[1];
      __syncthreads();
      if (kt < qt) {                        // prefetch next tile; overlaps compute below
        const unsigned short* kp = kbase + (size_t)(kt + 1) * 4096;
        const unsigned short* vp = vbase + (size_t)(kt + 1) * 64;
        kreg[0] = *(const short8*)(kp + (size_t)c0 * 8);
        kreg[1] = *(const short8*)(kp + (size_t)c1 * 8);
        vreg[0] = *(const short8*)(vp + (size_t)(c0 >> 3) * 1024 + (c0 & 7) * 8);
        vreg[1] = *(const short8*)(vp + (size_t)(c1 >> 3) * 1024 + (c1 & 7) * 8);
      }

      // S = Q K^T (q pre-scaled by 0.125*log2e)
      f32x4 s[4];
      for (int j = 0; j < 4; ++j) s[j] = fzero;
      for (int ks = 0; ks < 2; ++ks) {
        short8 aq = *(const short8*)(Qs + (w * 16 + lr) * 72 + ks * 32 + lq * 8);
        short8 bk[4];
        for (int j = 0; j < 4; ++j)
          bk[j] = *(const short8*)(Ks + (j * 16 + lr) * 72 + ks * 32 + lq * 8);
        for (int j = 0; j < 4; ++j)
          s[j] = __builtin_amdgcn_mfma_f32_16x16x32_bf16(aq, bk[j], s[j], 0, 0, 0);
      }
      if (kt == qt) {                       // diagonal tile: causal mask
        int rowt = w * 16 + lq * 4;
        for (int j = 0; j < 4; ++j) {
          int colt = j * 16 + lr;
          for (int r = 0; r < 4; ++r)
            if (colt > rowt + r) s[j][r] = -1e30f;
        }
      }
      // p = exp2(s); accumulate l per-lane; stash P (C-layout -> A-layout via LDS)
      for (int r = 0; r < 4; ++r) {
        int prow = (lq * 4 + r) * 72;
        float acc = 0.0f;
        for (int j = 0; j < 4; ++j) {
          float p = __builtin_amdgcn_exp2f(s[j][r]);
          acc += p;
          union { float f; unsigned int u; } cv; cv.f = p;
          Pw[prow + j * 16 + lr] = (unsigned short)((cv.u + 0x8000u) >> 16);
        }
        l_s[r] += acc;
      }
      // O += P V (same-wave DS in-order; compiler emits lgkm waits)
      for (int ks = 0; ks < 2; ++ks) {
        short8 ap = *(const short8*)(Pw + lr * 72 + ks * 32 + lq * 8);
        short8 bv[4];
        for (int jd = 0; jd < 4; ++jd)
          bv[jd] = *(const short8*)(Vt + (jd * 16 + lr) * 72 + ks * 32 + lq * 8);
        for (int jd = 0; jd < 4; ++jd)
          o[jd] = __builtin_amdgcn_mfma_f32_16x16x32_bf16(ap, bv[jd], o[jd], 0, 0, 0);
      }
    }

    // epilogue: reduce l across the 16 col-lanes, scale, store
    for (int r = 0; r < 4; ++r) {
      float lv = l_s[r];
      for (int off = 1; off < 16; off <<= 1)
        lv += __shfl_xor(lv, off, 16);
      l_s[r] = 1.0f / lv;
    }
    int t = q0 + w * 16 + lq * 4;
    for (int jd = 0; jd < 4; ++jd) {
      int d = jd * 16 + lr;
      for (int r = 0; r < 4; ++r)
        y[((size_t)b * 1024 + t + r) * 768 + h * 64 + d] = f2b(o[jd][r] * l_s[r]);
    }
  }
}

// ---------------- GEMM 2: out = y @ w_proj + b (r3 version) ----------------

__global__ __launch_bounds__(256, 2) void gemm_proj(
    const unsigned short* __restrict__ A,   // y [8192][768]
    const unsigned short* __restrict__ Bt,  // wpT [768][768]
    const float* __restrict__ bias,         // [768]
    float* __restrict__ out)                // [8192][768] fp32
{
  __shared__ unsigned short As[128 * 32];
  __shared__ unsigned short Bs[128 * 32];
  const int tid = threadIdx.x;
  const int w = tid >> 6, lane = tid & 63;
  const int wm = w >> 1, wn = w & 1;
  const int lr = lane & 15, lq = lane >> 4;
  const int m0 = blockIdx.x * 128, n0 = blockIdx.y * 128;
  const f32x4 fzero = {0.f, 0.f, 0.f, 0.f};

  f32x4 acc[4][4];
  for (int i = 0; i < 4; ++i) for (int j = 0; j < 4; ++j) acc[i][j] = fzero;

  for (int kk0 = 0; kk0 < 768; kk0 += 32) {
    __syncthreads();
    for (int c = 0; c < 2; ++c) {
      int base = (c * 4 + w) * 1024;
      int e = (base >> 1) + lane * 8;
      int row = e >> 5, kc = e & 31;
      ASYNC16(A  + (size_t)(m0 + row) * 768 + kk0 + kc, (char*)As + base);
      ASYNC16(Bt + (size_t)(n0 + row) * 768 + kk0 + kc, (char*)Bs + base);
    }
    __builtin_amdgcn_s_waitcnt(0);
    __syncthreads();

    short8 a[4], b[4];
    for (int i = 0; i < 4; ++i)
      a[i] = *(const short8*)(As + (wm * 64 + i * 16 + lr) * 32 + lq * 8);
    for (int j = 0; j < 4; ++j)
      b[j] = *(const short8*)(Bs + (wn * 64 + j * 16 + lr) * 32 + lq * 8);
    for (int i = 0; i < 4; ++i)
      for (int j = 0; j < 4; ++j)
        acc[i][j] = __builtin_amdgcn_mfma_f32_16x16x32_bf16(a[i], b[j], acc[i][j], 0, 0, 0);
  }

  for (int j = 0; j < 4; ++j) {
    int col = n0 + wn * 64 + j * 16 + lr;
    float bv = bias[col];
    for (int i = 0; i < 4; ++i) {
      int row0 = m0 + wm * 64 + i * 16 + lq * 4;
      for (int r = 0; r < 4; ++r)
        out[(size_t)(row0 + r) * 768 + col] = acc[i][j][r] + bv;
    }
  }
}

// ---------------- launch ----------------

extern "C" void kernel_launch(void* const* d_in, const int* in_sizes, int n_in,
                              void* d_out, int out_size, void* d_ws, size_t ws_size,
                              hipStream_t stream) {
  const float* x      = (const float*)d_in[0];
  const float* w_attn = (const float*)d_in[1];
  const float* b_attn = (const float*)d_in[2];
  const float* w_proj = (const float*)d_in[3];
  const float* b_proj = (const float*)d_in[4];
  float* out = (float*)d_out;

  char* p = (char*)d_ws;
  unsigned short* xb  = (unsigned short*)p; p += (size_t)8192 * 768 * 2;
  unsigned short* waT = (unsigned short*)p; p += (size_t)2304 * 768 * 2;
  unsigned short* wpT = (unsigned short*)p; p += (size_t)768 * 768 * 2;
  unsigned short* qb  = (unsigned short*)p; p += (size_t)96 * 1024 * 64 * 2;
  unsigned short* kb  = (unsigned short*)p; p += (size_t)96 * 1024 * 64 * 2;
  unsigned short* vTb = (unsigned short*)p; p += (size_t)96 * 64 * 1024 * 2;
  unsigned short* yb  = (unsigned short*)p; p += (size_t)8192 * 768 * 2;

  prep<<<3648, 256, 0, stream>>>(x, xb, w_attn, waT, w_proj, wpT);
  gemm_qkv<<<dim3(64, 18), 256, 0, stream>>>(xb, waT, b_attn, qb, kb, vTb);
  attn<<<768, 256, 0, stream>>>(qb, kb, vTb, yb);
  gemm_proj<<<dim3(64, 6), 256, 0, stream>>>(yb, wpT, b_proj, out);
}

// Round 8
// 188.454 us; speedup vs baseline: 2.3517x; 1.0028x over previous
//
#include <hip/hip_runtime.h>
#include <cstdint>
#include <cstddef>

typedef __attribute__((ext_vector_type(8))) short short8;     // 8 bf16 (4 VGPRs)
typedef __attribute__((ext_vector_type(4))) float f32x4;      // MFMA acc
typedef __attribute__((ext_vector_type(4))) unsigned short u16x4;

#define ASYNC16(gp, lp) \
  __builtin_amdgcn_global_load_lds((const __attribute__((address_space(1))) unsigned int*)(gp), \
                                   (__attribute__((address_space(3))) unsigned int*)(lp), 16, 0, 0)

__device__ __forceinline__ unsigned short f2b(float f) {
  union { float f; unsigned int u; } c; c.f = f;
  unsigned int u = c.u;
  return (unsigned short)((u + 0x7fffu + ((u >> 16) & 1u)) >> 16);
}

// ---------------- merged prep: x->bf16, w_attn->waT, w_proj->wpT ----------------

__global__ __launch_bounds__(256) void prep(
    const float* __restrict__ x, unsigned short* __restrict__ xb,
    const float* __restrict__ w_attn, unsigned short* __restrict__ waT,
    const float* __restrict__ w_proj, unsigned short* __restrict__ wpT) {
  __shared__ unsigned short Ts[64][65];
  const int bb = blockIdx.x;
  const int tid = threadIdx.x;
  if (bb < 3072) {
    int i = (bb * 256 + tid) * 8;
    const float* px = x + i;
    short8 v;
    for (int e = 0; e < 8; ++e) ((unsigned short*)&v)[e] = f2b(px[e]);
    *(short8*)(xb + i) = v;
    return;
  }
  const float* W; unsigned short* WT; int Kd, Nd, n0, k0;
  if (bb < 3504) {
    int t = bb - 3072; W = w_attn; WT = waT; Kd = 768; Nd = 2304;
    n0 = (t % 36) * 64; k0 = (t / 36) * 64;
  } else {
    int t = bb - 3504; W = w_proj; WT = wpT; Kd = 768; Nd = 768;
    n0 = (t % 12) * 64; k0 = (t / 12) * 64;
  }
  for (int idx = tid; idx < 4096; idx += 256) {
    int lr = idx >> 6, lc = idx & 63;
    Ts[lr][lc] = f2b(W[(size_t)(k0 + lr) * Nd + n0 + lc]);
  }
  __syncthreads();
  for (int idx = tid; idx < 4096; idx += 256) {
    int nr = idx >> 6, kc = idx & 63;
    WT[(size_t)(n0 + nr) * Kd + k0 + kc] = Ts[kc][nr];
  }
}

// ---------------- GEMM 1: qkv = x @ w_attn + b, scatter to q/k/vT ----------------
// r3 structure (measured 62.5 us). r4/r5/r6 variants all neutral-or-worse;
// cost model: ~95 B/cyc/CU LDS traffic == ds pipe sustained rate -> LDS-bound.

__global__ __launch_bounds__(256, 2) void gemm_qkv(
    const unsigned short* __restrict__ A,   // xb [8192][768]
    const unsigned short* __restrict__ Bt,  // waT [2304][768]
    const float* __restrict__ bias,         // [2304]
    unsigned short* __restrict__ q,         // [96][1024][64], pre-scaled by 0.125*log2(e)
    unsigned short* __restrict__ k,         // [96][1024][64]
    unsigned short* __restrict__ vT)        // [96][64][1024]
{
  __shared__ unsigned short As[128 * 32];
  __shared__ unsigned short Bs[128 * 32];
  const int tid = threadIdx.x;
  const int w = tid >> 6, lane = tid & 63;
  const int wm = w >> 1, wn = w & 1;
  const int lr = lane & 15, lq = lane >> 4;
  const int m0 = blockIdx.x * 128, n0 = blockIdx.y * 128;
  const f32x4 fzero = {0.f, 0.f, 0.f, 0.f};

  f32x4 acc[4][4];
  for (int i = 0; i < 4; ++i) for (int j = 0; j < 4; ++j) acc[i][j] = fzero;

  for (int kk0 = 0; kk0 < 768; kk0 += 32) {
    __syncthreads();
    for (int c = 0; c < 2; ++c) {
      int base = (c * 4 + w) * 1024;
      int e = (base >> 1) + lane * 8;
      int row = e >> 5, kc = e & 31;
      ASYNC16(A  + (size_t)(m0 + row) * 768 + kk0 + kc, (char*)As + base);
      ASYNC16(Bt + (size_t)(n0 + row) * 768 + kk0 + kc, (char*)Bs + base);
    }
    __builtin_amdgcn_s_waitcnt(0);
    __syncthreads();

    short8 a[4], b[4];
    for (int i = 0; i < 4; ++i)
      a[i] = *(const short8*)(As + (wm * 64 + i * 16 + lr) * 32 + lq * 8);
    for (int j = 0; j < 4; ++j)
      b[j] = *(const short8*)(Bs + (wn * 64 + j * 16 + lr) * 32 + lq * 8);
    for (int i = 0; i < 4; ++i)
      for (int j = 0; j < 4; ++j)
        acc[i][j] = __builtin_amdgcn_mfma_f32_16x16x32_bf16(a[i], b[j], acc[i][j], 0, 0, 0);
  }

  const int colbase = n0 + wn * 64;
  const int sec = colbase / 768;                // 0=q, 1=k, 2=v (block-uniform)
  const float QSCALE = 0.18033688011112042f;    // 0.125 * log2(e)
  for (int j = 0; j < 4; ++j) {
    int col = colbase + j * 16 + lr;
    int cc = col - sec * 768;
    int h = cc >> 6, d = cc & 63;
    float bv = bias[col];
    for (int i = 0; i < 4; ++i) {
      int row0 = m0 + wm * 64 + i * 16 + lq * 4;
      int bidx = row0 >> 10, t0 = row0 & 1023;
      int bh = bidx * 12 + h;
      if (sec == 0) {
        for (int r = 0; r < 4; ++r)
          q[((size_t)bh * 1024 + t0 + r) * 64 + d] = f2b((acc[i][j][r] + bv) * QSCALE);
      } else if (sec == 1) {
        for (int r = 0; r < 4; ++r)
          k[((size_t)bh * 1024 + t0 + r) * 64 + d] = f2b(acc[i][j][r] + bv);
      } else {
        u16x4 pv;
        pv[0] = f2b(acc[i][j][0] + bv);
        pv[1] = f2b(acc[i][j][1] + bv);
        pv[2] = f2b(acc[i][j][2] + bv);
        pv[3] = f2b(acc[i][j][3] + bv);
        *(u16x4*)(vT + ((size_t)bh * 64 + d) * 1024 + t0) = pv;
      }
    }
  }
}

// ---------------- flash attention, dual-Q-tile over one K/V stream ----------------
// grid 768: block g = (qp = g/96 in [0,8), bh = g%96). Block holds Q-tiles qp
// (strip0) and 15-qp (strip1), loops kt = 0..15-qp staging K/V ONCE. Compute
// balanced: every block does 17 strip-units. bk frags shared by both strips.

__global__ __launch_bounds__(256, 3) void attn(
    const unsigned short* __restrict__ q,
    const unsigned short* __restrict__ kk,
    const unsigned short* __restrict__ vT,
    unsigned short* __restrict__ y)         // [8192][768]
{
  __shared__ unsigned short Qs[128 * 72];   // strip0 rows 0-63, strip1 rows 64-127
  __shared__ unsigned short Ks[64 * 72];
  __shared__ unsigned short Vt[64 * 72];    // [d][t]
  __shared__ unsigned short Ps[4 * 16 * 72];

  const int tid = threadIdx.x;
  const int w = tid >> 6, lane = tid & 63;
  const int lr = lane & 15, lq = lane >> 4;
  const int g = blockIdx.x;
  const int bh = g % 96;
  const int qp = g / 96;                    // strip0 tile
  const int qt1 = 15 - qp;                  // strip1 tile
  const int b = bh / 12, h = bh - b * 12;
  const f32x4 fzero = {0.f, 0.f, 0.f, 0.f};

  unsigned short* Pw = Ps + w * 16 * 72;
  const unsigned short* kbase = kk + (size_t)bh * 65536;
  const unsigned short* vbase = vT + (size_t)bh * 65536;

  // load both Q tiles (each 64 rows x 64 d = 512 chunks of 8 elems)
  {
    const unsigned short* qa = q + ((size_t)bh * 1024 + qp * 64) * 64;
    const unsigned short* qb = q + ((size_t)bh * 1024 + qt1 * 64) * 64;
    for (int c = tid; c < 512; c += 256) {
      int row = c >> 3, d0 = (c & 7) * 8;
      *(short8*)(Qs + row * 72 + d0)        = *(const short8*)(qa + (size_t)c * 8);
      *(short8*)(Qs + (row + 64) * 72 + d0) = *(const short8*)(qb + (size_t)c * 8);
    }
  }

  const int c0 = tid, c1 = tid + 256;
  short8 kreg[2], vreg[2];
  kreg[0] = *(const short8*)(kbase + (size_t)c0 * 8);
  kreg[1] = *(const short8*)(kbase + (size_t)c1 * 8);
  vreg[0] = *(const short8*)(vbase + (size_t)(c0 >> 3) * 1024 + (c0 & 7) * 8);
  vreg[1] = *(const short8*)(vbase + (size_t)(c1 >> 3) * 1024 + (c1 & 7) * 8);

  f32x4 o0[4], o1[4];
  float l0[4], l1[4];
  for (int jd = 0; jd < 4; ++jd) { o0[jd] = fzero; o1[jd] = fzero; }
  for (int r = 0; r < 4; ++r) { l0[r] = 0.0f; l1[r] = 0.0f; }

  const int nkt = qt1 + 1;                  // kt = 0..qt1

  for (int kt = 0; kt < nkt; ++kt) {
    __syncthreads();                        // prev iter's LDS reads done (+Q visible)
    *(short8*)(Ks + (c0 >> 3) * 72 + (c0 & 7) * 8) = kreg[0];
    *(short8*)(Ks + (c1 >> 3) * 72 + (c1 & 7) * 8) = kreg[1];
    *(short8*)(Vt + (c0 >> 3) * 72 + (c0 & 7) * 8) = vreg[0];
    *(short8*)(Vt + (c1 >> 3) * 72 + (c1 & 7) * 8) = vreg[1];
    __syncthreads();
    if (kt + 1 < nkt) {                     // prefetch next K/V tile
      const unsigned short* kp = kbase + (size_t)(kt + 1) * 4096;
      const unsigned short* vp = vbase + (size_t)(kt + 1) * 64;
      kreg[0] = *(const short8*)(kp + (size_t)c0 * 8);
      kreg[1] = *(const short8*)(kp + (size_t)c1 * 8);
      vreg[0] = *(const short8*)(vp + (size_t)(c0 >> 3) * 1024 + (c0 & 7) * 8);
      vreg[1] = *(const short8*)(vp + (size_t)(c1 >> 3) * 1024 + (c1 & 7) * 8);
    }

    // shared K fragments for both strips
    short8 bk[2][4];
    for (int ks = 0; ks < 2; ++ks)
      for (int j = 0; j < 4; ++j)
        bk[ks][j] = *(const short8*)(Ks + (j * 16 + lr) * 72 + ks * 32 + lq * 8);

    // ---- strip 0 (tile qp): active while kt <= qp (block-uniform branch) ----
    if (kt <= qp) {
      f32x4 s[4];
      for (int j = 0; j < 4; ++j) s[j] = fzero;
      for (int ks = 0; ks < 2; ++ks) {
        short8 aq = *(const short8*)(Qs + (w * 16 + lr) * 72 + ks * 32 + lq * 8);
        for (int j = 0; j < 4; ++j)
          s[j] = __builtin_amdgcn_mfma_f32_16x16x32_bf16(aq, bk[ks][j], s[j], 0, 0, 0);
      }
      if (kt == qp) {                       // diagonal
        int rowt = w * 16 + lq * 4;
        for (int j = 0; j < 4; ++j) {
          int colt = j * 16 + lr;
          for (int r = 0; r < 4; ++r)
            if (colt > rowt + r) s[j][r] = -1e30f;
        }
      }
      for (int r = 0; r < 4; ++r) {
        int prow = (lq * 4 + r) * 72;
        float acc = 0.0f;
        for (int j = 0; j < 4; ++j) {
          float p = __builtin_amdgcn_exp2f(s[j][r]);
          acc += p;
          union { float f; unsigned int u; } cv; cv.f = p;
          Pw[prow + j * 16 + lr] = (unsigned short)((cv.u + 0x8000u) >> 16);
        }
        l0[r] += acc;
      }
      for (int ks = 0; ks < 2; ++ks) {
        short8 ap = *(const short8*)(Pw + lr * 72 + ks * 32 + lq * 8);
        short8 bv[4];
        for (int jd = 0; jd < 4; ++jd)
          bv[jd] = *(const short8*)(Vt + (jd * 16 + lr) * 72 + ks * 32 + lq * 8);
        for (int jd = 0; jd < 4; ++jd)
          o0[jd] = __builtin_amdgcn_mfma_f32_16x16x32_bf16(ap, bv[jd], o0[jd], 0, 0, 0);
      }
    }

    // ---- strip 1 (tile 15-qp): active for all kt in loop ----
    {
      f32x4 s[4];
      for (int j = 0; j < 4; ++j) s[j] = fzero;
      for (int ks = 0; ks < 2; ++ks) {
        short8 aq = *(const short8*)(Qs + (64 + w * 16 + lr) * 72 + ks * 32 + lq * 8);
        for (int j = 0; j < 4; ++j)
          s[j] = __builtin_amdgcn_mfma_f32_16x16x32_bf16(aq, bk[ks][j], s[j], 0, 0, 0);
      }
      if (kt == qt1) {                      // diagonal
        int rowt = w * 16 + lq * 4;
        for (int j = 0; j < 4; ++j) {
          int colt = j * 16 + lr;
          for (int r = 0; r < 4; ++r)
            if (colt > rowt + r) s[j][r] = -1e30f;
        }
      }
      for (int r = 0; r < 4; ++r) {
        int prow = (lq * 4 + r) * 72;
        float acc = 0.0f;
        for (int j = 0; j < 4; ++j) {
          float p = __builtin_amdgcn_exp2f(s[j][r]);
          acc += p;
          union { float f; unsigned int u; } cv; cv.f = p;
          Pw[prow + j * 16 + lr] = (unsigned short)((cv.u + 0x8000u) >> 16);
        }
        l1[r] += acc;
      }
      for (int ks = 0; ks < 2; ++ks) {
        short8 ap = *(const short8*)(Pw + lr * 72 + ks * 32 + lq * 8);
        short8 bv[4];
        for (int jd = 0; jd < 4; ++jd)
          bv[jd] = *(const short8*)(Vt + (jd * 16 + lr) * 72 + ks * 32 + lq * 8);
        for (int jd = 0; jd < 4; ++jd)
          o1[jd] = __builtin_amdgcn_mfma_f32_16x16x32_bf16(ap, bv[jd], o1[jd], 0, 0, 0);
      }
    }
  }

  // epilogue: both strips
  for (int r = 0; r < 4; ++r) {
    float a0 = l0[r], a1 = l1[r];
    for (int off = 1; off < 16; off <<= 1) {
      a0 += __shfl_xor(a0, off, 16);
      a1 += __shfl_xor(a1, off, 16);
    }
    l0[r] = 1.0f / a0;
    l1[r] = 1.0f / a1;
  }
  int t0 = qp * 64 + w * 16 + lq * 4;
  int t1 = qt1 * 64 + w * 16 + lq * 4;
  for (int jd = 0; jd < 4; ++jd) {
    int d = jd * 16 + lr;
    for (int r = 0; r < 4; ++r) {
      y[((size_t)b * 1024 + t0 + r) * 768 + h * 64 + d] = f2b(o0[jd][r] * l0[r]);
      y[((size_t)b * 1024 + t1 + r) * 768 + h * 64 + d] = f2b(o1[jd][r] * l1[r]);
    }
  }
}

// ---------------- GEMM 2: out = y @ w_proj + b ----------------
// 64x128 tile, grid 128x6 = 768 blocks = exactly 3/CU (was 384 = 1.5/CU).
// Clean row-major epilogue (no scatter -> no r6-style write amplification).

__global__ __launch_bounds__(256, 3) void gemm_proj(
    const unsigned short* __restrict__ A,   // y [8192][768]
    const unsigned short* __restrict__ Bt,  // wpT [768][768]
    const float* __restrict__ bias,         // [768]
    float* __restrict__ out)                // [8192][768] fp32
{
  __shared__ unsigned short As[64 * 32];    // 4 KB
  __shared__ unsigned short Bs[128 * 32];   // 8 KB
  const int tid = threadIdx.x;
  const int w = tid >> 6, lane = tid & 63;
  const int wm = w >> 1, wn = w & 1;        // wave-tile 32 x 64
  const int lr = lane & 15, lq = lane >> 4;
  const int m0 = blockIdx.x * 64, n0 = blockIdx.y * 128;
  const f32x4 fzero = {0.f, 0.f, 0.f, 0.f};

  f32x4 acc[2][4];
  for (int i = 0; i < 2; ++i) for (int j = 0; j < 4; ++j) acc[i][j] = fzero;

  // A: one 1KB chunk per wave; B: two 1KB chunks per wave
  const int ea = (w * 1024 >> 1) + lane * 8;
  const int arow = ea >> 5, akc = ea & 31;
  int sbase[2], srow[2], skc[2];
  for (int c = 0; c < 2; ++c) {
    sbase[c] = (c * 4 + w) * 1024;
    int e = (sbase[c] >> 1) + lane * 8;
    srow[c] = e >> 5; skc[c] = e & 31;
  }

  for (int kk0 = 0; kk0 < 768; kk0 += 32) {
    __syncthreads();
    ASYNC16(A + (size_t)(m0 + arow) * 768 + kk0 + akc, (char*)As + w * 1024);
    for (int c = 0; c < 2; ++c)
      ASYNC16(Bt + (size_t)(n0 + srow[c]) * 768 + kk0 + skc[c], (char*)Bs + sbase[c]);
    __builtin_amdgcn_s_waitcnt(0);
    __syncthreads();

    short8 a[2], b[4];
    for (int i = 0; i < 2; ++i)
      a[i] = *(const short8*)(As + (wm * 32 + i * 16 + lr) * 32 + lq * 8);
    for (int j = 0; j < 4; ++j)
      b[j] = *(const short8*)(Bs + (wn * 64 + j * 16 + lr) * 32 + lq * 8);
    for (int i = 0; i < 2; ++i)
      for (int j = 0; j < 4; ++j)
        acc[i][j] = __builtin_amdgcn_mfma_f32_16x16x32_bf16(a[i], b[j], acc[i][j], 0, 0, 0);
  }

  for (int j = 0; j < 4; ++j) {
    int col = n0 + wn * 64 + j * 16 + lr;
    float bv = bias[col];
    for (int i = 0; i < 2; ++i) {
      int row0 = m0 + wm * 32 + i * 16 + lq * 4;
      for (int r = 0; r < 4; ++r)
        out[(size_t)(row0 + r) * 768 + col] = acc[i][j][r] + bv;
    }
  }
}

// ---------------- launch ----------------

extern "C" void kernel_launch(void* const* d_in, const int* in_sizes, int n_in,
                              void* d_out, int out_size, void* d_ws, size_t ws_size,
                              hipStream_t stream) {
  const float* x      = (const float*)d_in[0];
  const float* w_attn = (const float*)d_in[1];
  const float* b_attn = (const float*)d_in[2];
  const float* w_proj = (const float*)d_in[3];
  const float* b_proj = (const float*)d_in[4];
  float* out = (float*)d_out;

  char* p = (char*)d_ws;
  unsigned short* xb  = (unsigned short*)p; p += (size_t)8192 * 768 * 2;
  unsigned short* waT = (unsigned short*)p; p += (size_t)2304 * 768 * 2;
  unsigned short* wpT = (unsigned short*)p; p += (size_t)768 * 768 * 2;
  unsigned short* qb  = (unsigned short*)p; p += (size_t)96 * 1024 * 64 * 2;
  unsigned short* kb  = (unsigned short*)p; p += (size_t)96 * 1024 * 64 * 2;
  unsigned short* vTb = (unsigned short*)p; p += (size_t)96 * 64 * 1024 * 2;
  unsigned short* yb  = (unsigned short*)p; p += (size_t)8192 * 768 * 2;

  prep<<<3648, 256, 0, stream>>>(x, xb, w_attn, waT, w_proj, wpT);
  gemm_qkv<<<dim3(64, 18), 256, 0, stream>>>(xb, waT, b_attn, qb, kb, vTb);
  attn<<<768, 256, 0, stream>>>(qb, kb, vTb, yb);
  gemm_proj<<<dim3(128, 6), 256, 0, stream>>>(yb, wpT, b_proj, out);
}

// Round 9
// 182.751 us; speedup vs baseline: 2.4251x; 1.0312x over previous
//
#include <hip/hip_runtime.h>
#include <cstdint>
#include <cstddef>

typedef __attribute__((ext_vector_type(8))) short short8;     // 8 bf16 (4 VGPRs)
typedef __attribute__((ext_vector_type(4))) float f32x4;      // MFMA acc
typedef __attribute__((ext_vector_type(4))) unsigned short u16x4;

#define ASYNC16(gp, lp) \
  __builtin_amdgcn_global_load_lds((const __attribute__((address_space(1))) unsigned int*)(gp), \
                                   (__attribute__((address_space(3))) unsigned int*)(lp), 16, 0, 0)

__device__ __forceinline__ unsigned short f2b(float f) {
  union { float f; unsigned int u; } c; c.f = f;
  unsigned int u = c.u;
  return (unsigned short)((u + 0x7fffu + ((u >> 16) & 1u)) >> 16);
}

// ---------------- merged prep: x->bf16, w_attn->waT, w_proj->wpT ----------------

__global__ __launch_bounds__(256) void prep(
    const float* __restrict__ x, unsigned short* __restrict__ xb,
    const float* __restrict__ w_attn, unsigned short* __restrict__ waT,
    const float* __restrict__ w_proj, unsigned short* __restrict__ wpT) {
  __shared__ unsigned short Ts[64][65];
  const int bb = blockIdx.x;
  const int tid = threadIdx.x;
  if (bb < 3072) {
    int i = (bb * 256 + tid) * 8;
    const float* px = x + i;
    short8 v;
    for (int e = 0; e < 8; ++e) ((unsigned short*)&v)[e] = f2b(px[e]);
    *(short8*)(xb + i) = v;
    return;
  }
  const float* W; unsigned short* WT; int Kd, Nd, n0, k0;
  if (bb < 3504) {
    int t = bb - 3072; W = w_attn; WT = waT; Kd = 768; Nd = 2304;
    n0 = (t % 36) * 64; k0 = (t / 36) * 64;
  } else {
    int t = bb - 3504; W = w_proj; WT = wpT; Kd = 768; Nd = 768;
    n0 = (t % 12) * 64; k0 = (t / 12) * 64;
  }
  for (int idx = tid; idx < 4096; idx += 256) {
    int lr = idx >> 6, lc = idx & 63;
    Ts[lr][lc] = f2b(W[(size_t)(k0 + lr) * Nd + n0 + lc]);
  }
  __syncthreads();
  for (int idx = tid; idx < 4096; idx += 256) {
    int nr = idx >> 6, kc = idx & 63;
    WT[(size_t)(n0 + nr) * Kd + k0 + kc] = Ts[kc][nr];
  }
}

// ---------------- GEMM 1: qkv = x @ w_attn + b, scatter to q/k/vT ----------------
// BK=64: two 32-k sub-tiles per barrier pair (each keeps r3's 64B-row layout ->
// same bank behavior), 32 MFMA + 16 ds_read/iter, 12 iters (was 24). Per-iter
// serial chain amortized 2x; launch_bounds(256,4) caps regs at 128 (= 64 arch
// + 64 acc, exactly what r3 used) for up to 4 blocks/CU overlap.

__global__ __launch_bounds__(256, 4) void gemm_qkv(
    const unsigned short* __restrict__ A,   // xb [8192][768]
    const unsigned short* __restrict__ Bt,  // waT [2304][768]
    const float* __restrict__ bias,         // [2304]
    unsigned short* __restrict__ q,         // [96][1024][64], pre-scaled by 0.125*log2(e)
    unsigned short* __restrict__ k,         // [96][1024][64]
    unsigned short* __restrict__ vT)        // [96][64][1024]
{
  __shared__ unsigned short As[2][128 * 32];  // two 8KB sub-tiles (k-lo, k-hi)
  __shared__ unsigned short Bs[2][128 * 32];
  const int tid = threadIdx.x;
  const int w = tid >> 6, lane = tid & 63;
  const int wm = w >> 1, wn = w & 1;
  const int lr = lane & 15, lq = lane >> 4;
  const int m0 = blockIdx.x * 128, n0 = blockIdx.y * 128;
  const f32x4 fzero = {0.f, 0.f, 0.f, 0.f};

  f32x4 acc[4][4];
  for (int i = 0; i < 4; ++i) for (int j = 0; j < 4; ++j) acc[i][j] = fzero;

  for (int kk0 = 0; kk0 < 768; kk0 += 64) {
    __syncthreads();
    for (int ks = 0; ks < 2; ++ks)
      for (int c = 0; c < 2; ++c) {
        int base = (c * 4 + w) * 1024;          // byte offset within 8KB sub-tile
        int e = (base >> 1) + lane * 8;
        int row = e >> 5, kc = e & 31;
        ASYNC16(A  + (size_t)(m0 + row) * 768 + kk0 + ks * 32 + kc, (char*)As[ks] + base);
        ASYNC16(Bt + (size_t)(n0 + row) * 768 + kk0 + ks * 32 + kc, (char*)Bs[ks] + base);
      }
    __builtin_amdgcn_s_waitcnt(0);
    __syncthreads();

    for (int ks = 0; ks < 2; ++ks) {
      short8 a[4], b[4];
      for (int i = 0; i < 4; ++i)
        a[i] = *(const short8*)(As[ks] + (wm * 64 + i * 16 + lr) * 32 + lq * 8);
      for (int j = 0; j < 4; ++j)
        b[j] = *(const short8*)(Bs[ks] + (wn * 64 + j * 16 + lr) * 32 + lq * 8);
      for (int i = 0; i < 4; ++i)
        for (int j = 0; j < 4; ++j)
          acc[i][j] = __builtin_amdgcn_mfma_f32_16x16x32_bf16(a[i], b[j], acc[i][j], 0, 0, 0);
    }
  }

  const int colbase = n0 + wn * 64;
  const int sec = colbase / 768;                // 0=q, 1=k, 2=v (block-uniform)
  const float QSCALE = 0.18033688011112042f;    // 0.125 * log2(e)
  for (int j = 0; j < 4; ++j) {
    int col = colbase + j * 16 + lr;
    int cc = col - sec * 768;
    int h = cc >> 6, d = cc & 63;
    float bv = bias[col];
    for (int i = 0; i < 4; ++i) {
      int row0 = m0 + wm * 64 + i * 16 + lq * 4;
      int bidx = row0 >> 10, t0 = row0 & 1023;
      int bh = bidx * 12 + h;
      if (sec == 0) {
        for (int r = 0; r < 4; ++r)
          q[((size_t)bh * 1024 + t0 + r) * 64 + d] = f2b((acc[i][j][r] + bv) * QSCALE);
      } else if (sec == 1) {
        for (int r = 0; r < 4; ++r)
          k[((size_t)bh * 1024 + t0 + r) * 64 + d] = f2b(acc[i][j][r] + bv);
      } else {
        u16x4 pv;
        pv[0] = f2b(acc[i][j][0] + bv);
        pv[1] = f2b(acc[i][j][1] + bv);
        pv[2] = f2b(acc[i][j][2] + bv);
        pv[3] = f2b(acc[i][j][3] + bv);
        *(u16x4*)(vT + ((size_t)bh * 64 + d) * 1024 + t0) = pv;
      }
    }
  }
}

// ---------------- flash attention, dual-Q-tile over one K/V stream ----------------

__global__ __launch_bounds__(256, 3) void attn(
    const unsigned short* __restrict__ q,
    const unsigned short* __restrict__ kk,
    const unsigned short* __restrict__ vT,
    unsigned short* __restrict__ y)         // [8192][768]
{
  __shared__ unsigned short Qs[128 * 72];   // strip0 rows 0-63, strip1 rows 64-127
  __shared__ unsigned short Ks[64 * 72];
  __shared__ unsigned short Vt[64 * 72];    // [d][t]
  __shared__ unsigned short Ps[4 * 16 * 72];

  const int tid = threadIdx.x;
  const int w = tid >> 6, lane = tid & 63;
  const int lr = lane & 15, lq = lane >> 4;
  const int g = blockIdx.x;
  const int bh = g % 96;
  const int qp = g / 96;                    // strip0 tile
  const int qt1 = 15 - qp;                  // strip1 tile
  const int b = bh / 12, h = bh - b * 12;
  const f32x4 fzero = {0.f, 0.f, 0.f, 0.f};

  unsigned short* Pw = Ps + w * 16 * 72;
  const unsigned short* kbase = kk + (size_t)bh * 65536;
  const unsigned short* vbase = vT + (size_t)bh * 65536;

  {
    const unsigned short* qa = q + ((size_t)bh * 1024 + qp * 64) * 64;
    const unsigned short* qb = q + ((size_t)bh * 1024 + qt1 * 64) * 64;
    for (int c = tid; c < 512; c += 256) {
      int row = c >> 3, d0 = (c & 7) * 8;
      *(short8*)(Qs + row * 72 + d0)        = *(const short8*)(qa + (size_t)c * 8);
      *(short8*)(Qs + (row + 64) * 72 + d0) = *(const short8*)(qb + (size_t)c * 8);
    }
  }

  const int c0 = tid, c1 = tid + 256;
  short8 kreg[2], vreg[2];
  kreg[0] = *(const short8*)(kbase + (size_t)c0 * 8);
  kreg[1] = *(const short8*)(kbase + (size_t)c1 * 8);
  vreg[0] = *(const short8*)(vbase + (size_t)(c0 >> 3) * 1024 + (c0 & 7) * 8);
  vreg[1] = *(const short8*)(vbase + (size_t)(c1 >> 3) * 1024 + (c1 & 7) * 8);

  f32x4 o0[4], o1[4];
  float l0[4], l1[4];
  for (int jd = 0; jd < 4; ++jd) { o0[jd] = fzero; o1[jd] = fzero; }
  for (int r = 0; r < 4; ++r) { l0[r] = 0.0f; l1[r] = 0.0f; }

  const int nkt = qt1 + 1;

  for (int kt = 0; kt < nkt; ++kt) {
    __syncthreads();
    *(short8*)(Ks + (c0 >> 3) * 72 + (c0 & 7) * 8) = kreg[0];
    *(short8*)(Ks + (c1 >> 3) * 72 + (c1 & 7) * 8) = kreg[1];
    *(short8*)(Vt + (c0 >> 3) * 72 + (c0 & 7) * 8) = vreg[0];
    *(short8*)(Vt + (c1 >> 3) * 72 + (c1 & 7) * 8) = vreg[1];
    __syncthreads();
    if (kt + 1 < nkt) {
      const unsigned short* kp = kbase + (size_t)(kt + 1) * 4096;
      const unsigned short* vp = vbase + (size_t)(kt + 1) * 64;
      kreg[0] = *(const short8*)(kp + (size_t)c0 * 8);
      kreg[1] = *(const short8*)(kp + (size_t)c1 * 8);
      vreg[0] = *(const short8*)(vp + (size_t)(c0 >> 3) * 1024 + (c0 & 7) * 8);
      vreg[1] = *(const short8*)(vp + (size_t)(c1 >> 3) * 1024 + (c1 & 7) * 8);
    }

    short8 bk[2][4];
    for (int ks = 0; ks < 2; ++ks)
      for (int j = 0; j < 4; ++j)
        bk[ks][j] = *(const short8*)(Ks + (j * 16 + lr) * 72 + ks * 32 + lq * 8);

    if (kt <= qp) {                         // strip 0 (block-uniform branch)
      f32x4 s[4];
      for (int j = 0; j < 4; ++j) s[j] = fzero;
      for (int ks = 0; ks < 2; ++ks) {
        short8 aq = *(const short8*)(Qs + (w * 16 + lr) * 72 + ks * 32 + lq * 8);
        for (int j = 0; j < 4; ++j)
          s[j] = __builtin_amdgcn_mfma_f32_16x16x32_bf16(aq, bk[ks][j], s[j], 0, 0, 0);
      }
      if (kt == qp) {
        int rowt = w * 16 + lq * 4;
        for (int j = 0; j < 4; ++j) {
          int colt = j * 16 + lr;
          for (int r = 0; r < 4; ++r)
            if (colt > rowt + r) s[j][r] = -1e30f;
        }
      }
      for (int r = 0; r < 4; ++r) {
        int prow = (lq * 4 + r) * 72;
        float acc = 0.0f;
        for (int j = 0; j < 4; ++j) {
          float p = __builtin_amdgcn_exp2f(s[j][r]);
          acc += p;
          union { float f; unsigned int u; } cv; cv.f = p;
          Pw[prow + j * 16 + lr] = (unsigned short)((cv.u + 0x8000u) >> 16);
        }
        l0[r] += acc;
      }
      for (int ks = 0; ks < 2; ++ks) {
        short8 ap = *(const short8*)(Pw + lr * 72 + ks * 32 + lq * 8);
        short8 bv[4];
        for (int jd = 0; jd < 4; ++jd)
          bv[jd] = *(const short8*)(Vt + (jd * 16 + lr) * 72 + ks * 32 + lq * 8);
        for (int jd = 0; jd < 4; ++jd)
          o0[jd] = __builtin_amdgcn_mfma_f32_16x16x32_bf16(ap, bv[jd], o0[jd], 0, 0, 0);
      }
    }

    {                                       // strip 1 (always active)
      f32x4 s[4];
      for (int j = 0; j < 4; ++j) s[j] = fzero;
      for (int ks = 0; ks < 2; ++ks) {
        short8 aq = *(const short8*)(Qs + (64 + w * 16 + lr) * 72 + ks * 32 + lq * 8);
        for (int j = 0; j < 4; ++j)
          s[j] = __builtin_amdgcn_mfma_f32_16x16x32_bf16(aq, bk[ks][j], s[j], 0, 0, 0);
      }
      if (kt == qt1) {
        int rowt = w * 16 + lq * 4;
        for (int j = 0; j < 4; ++j) {
          int colt = j * 16 + lr;
          for (int r = 0; r < 4; ++r)
            if (colt > rowt + r) s[j][r] = -1e30f;
        }
      }
      for (int r = 0; r < 4; ++r) {
        int prow = (lq * 4 + r) * 72;
        float acc = 0.0f;
        for (int j = 0; j < 4; ++j) {
          float p = __builtin_amdgcn_exp2f(s[j][r]);
          acc += p;
          union { float f; unsigned int u; } cv; cv.f = p;
          Pw[prow + j * 16 + lr] = (unsigned short)((cv.u + 0x8000u) >> 16);
        }
        l1[r] += acc;
      }
      for (int ks = 0; ks < 2; ++ks) {
        short8 ap = *(const short8*)(Pw + lr * 72 + ks * 32 + lq * 8);
        short8 bv[4];
        for (int jd = 0; jd < 4; ++jd)
          bv[jd] = *(const short8*)(Vt + (jd * 16 + lr) * 72 + ks * 32 + lq * 8);
        for (int jd = 0; jd < 4; ++jd)
          o1[jd] = __builtin_amdgcn_mfma_f32_16x16x32_bf16(ap, bv[jd], o1[jd], 0, 0, 0);
      }
    }
  }

  for (int r = 0; r < 4; ++r) {
    float a0 = l0[r], a1 = l1[r];
    for (int off = 1; off < 16; off <<= 1) {
      a0 += __shfl_xor(a0, off, 16);
      a1 += __shfl_xor(a1, off, 16);
    }
    l0[r] = 1.0f / a0;
    l1[r] = 1.0f / a1;
  }
  int t0 = qp * 64 + w * 16 + lq * 4;
  int t1 = qt1 * 64 + w * 16 + lq * 4;
  for (int jd = 0; jd < 4; ++jd) {
    int d = jd * 16 + lr;
    for (int r = 0; r < 4; ++r) {
      y[((size_t)b * 1024 + t0 + r) * 768 + h * 64 + d] = f2b(o0[jd][r] * l0[r]);
      y[((size_t)b * 1024 + t1 + r) * 768 + h * 64 + d] = f2b(o1[jd][r] * l1[r]);
    }
  }
}

// ---------------- GEMM 2: out = y @ w_proj + b ----------------
// 64x128 tile, grid 128x6 = 768 = 3/CU; BK=64 (12 iters) + launch_bounds(256,4).

__global__ __launch_bounds__(256, 4) void gemm_proj(
    const unsigned short* __restrict__ A,   // y [8192][768]
    const unsigned short* __restrict__ Bt,  // wpT [768][768]
    const float* __restrict__ bias,         // [768]
    float* __restrict__ out)                // [8192][768] fp32
{
  __shared__ unsigned short As[2][64 * 32];   // two 4KB sub-tiles
  __shared__ unsigned short Bs[2][128 * 32];  // two 8KB sub-tiles
  const int tid = threadIdx.x;
  const int w = tid >> 6, lane = tid & 63;
  const int wm = w >> 1, wn = w & 1;        // wave-tile 32 x 64
  const int lr = lane & 15, lq = lane >> 4;
  const int m0 = blockIdx.x * 64, n0 = blockIdx.y * 128;
  const f32x4 fzero = {0.f, 0.f, 0.f, 0.f};

  f32x4 acc[2][4];
  for (int i = 0; i < 2; ++i) for (int j = 0; j < 4; ++j) acc[i][j] = fzero;

  // A sub-tile: 4KB = 4 chunks (1 per wave); B sub-tile: 8KB = 8 chunks (2/wave)
  const int ea = (w * 1024 >> 1) + lane * 8;
  const int arow = ea >> 5, akc = ea & 31;

  for (int kk0 = 0; kk0 < 768; kk0 += 64) {
    __syncthreads();
    for (int ks = 0; ks < 2; ++ks) {
      ASYNC16(A + (size_t)(m0 + arow) * 768 + kk0 + ks * 32 + akc, (char*)As[ks] + w * 1024);
      for (int c = 0; c < 2; ++c) {
        int base = (c * 4 + w) * 1024;
        int e = (base >> 1) + lane * 8;
        int row = e >> 5, kc = e & 31;
        ASYNC16(Bt + (size_t)(n0 + row) * 768 + kk0 + ks * 32 + kc, (char*)Bs[ks] + base);
      }
    }
    __builtin_amdgcn_s_waitcnt(0);
    __syncthreads();

    for (int ks = 0; ks < 2; ++ks) {
      short8 a[2], b[4];
      for (int i = 0; i < 2; ++i)
        a[i] = *(const short8*)(As[ks] + (wm * 32 + i * 16 + lr) * 32 + lq * 8);
      for (int j = 0; j < 4; ++j)
        b[j] = *(const short8*)(Bs[ks] + (wn * 64 + j * 16 + lr) * 32 + lq * 8);
      for (int i = 0; i < 2; ++i)
        for (int j = 0; j < 4; ++j)
          acc[i][j] = __builtin_amdgcn_mfma_f32_16x16x32_bf16(a[i], b[j], acc[i][j], 0, 0, 0);
    }
  }

  for (int j = 0; j < 4; ++j) {
    int col = n0 + wn * 64 + j * 16 + lr;
    float bv = bias[col];
    for (int i = 0; i < 2; ++i) {
      int row0 = m0 + wm * 32 + i * 16 + lq * 4;
      for (int r = 0; r < 4; ++r)
        out[(size_t)(row0 + r) * 768 + col] = acc[i][j][r] + bv;
    }
  }
}

// ---------------- launch ----------------

extern "C" void kernel_launch(void* const* d_in, const int* in_sizes, int n_in,
                              void* d_out, int out_size, void* d_ws, size_t ws_size,
                              hipStream_t stream) {
  const float* x      = (const float*)d_in[0];
  const float* w_attn = (const float*)d_in[1];
  const float* b_attn = (const float*)d_in[2];
  const float* w_proj = (const float*)d_in[3];
  const float* b_proj = (const float*)d_in[4];
  float* out = (float*)d_out;

  char* p = (char*)d_ws;
  unsigned short* xb  = (unsigned short*)p; p += (size_t)8192 * 768 * 2;
  unsigned short* waT = (unsigned short*)p; p += (size_t)2304 * 768 * 2;
  unsigned short* wpT = (unsigned short*)p; p += (size_t)768 * 768 * 2;
  unsigned short* qb  = (unsigned short*)p; p += (size_t)96 * 1024 * 64 * 2;
  unsigned short* kb  = (unsigned short*)p; p += (size_t)96 * 1024 * 64 * 2;
  unsigned short* vTb = (unsigned short*)p; p += (size_t)96 * 64 * 1024 * 2;
  unsigned short* yb  = (unsigned short*)p; p += (size_t)8192 * 768 * 2;

  prep<<<3648, 256, 0, stream>>>(x, xb, w_attn, waT, w_proj, wpT);
  gemm_qkv<<<dim3(64, 18), 256, 0, stream>>>(xb, waT, b_attn, qb, kb, vTb);
  attn<<<768, 256, 0, stream>>>(qb, kb, vTb, yb);
  gemm_proj<<<dim3(128, 6), 256, 0, stream>>>(yb, wpT, b_proj, out);
}